// Round 3
// baseline (1534.905 us; speedup 1.0000x reference)
//
#include <hip/hip_runtime.h>
#include <hip/hip_bf16.h>

typedef __attribute__((ext_vector_type(8))) short short8;
typedef __attribute__((ext_vector_type(4))) float f32x4;

#define TSEQ 2048
#define DMODEL 1024
#define NH 16
#define HD 64

__device__ __forceinline__ ushort f2bf(float f) {
    union { float f; unsigned int u; } c; c.f = f;
    unsigned int u = c.u + 0x7fffu + ((c.u >> 16) & 1u);   // RNE
    return (ushort)(u >> 16);
}

__device__ __forceinline__ float silu_f(float y) {
    return y / (1.f + __expf(-y));
}

// ---------------- convert x -> bf16 ----------------
__global__ void gdn_cvt_x(const float* __restrict__ x, ushort* __restrict__ xb) {
    int i = blockIdx.x * 256 + threadIdx.x;           // one float4 per thread
    float4 v = ((const float4*)x)[i];
    ushort4 o;
    o.x = f2bf(v.x); o.y = f2bf(v.y); o.z = f2bf(v.z); o.w = f2bf(v.w);
    ((ushort4*)xb)[i] = o;
}

// ------------- transpose+convert weights: W[k][n] f32 -> wt[z][n][k] bf16 -------------
__global__ void gdn_cvt_w(const float* __restrict__ Wq, const float* __restrict__ Wk,
                          const float* __restrict__ Wv, const float* __restrict__ Wg,
                          const float* __restrict__ Wo, ushort* __restrict__ wt) {
    __shared__ float tile[32][33];
    int z = blockIdx.z;
    const float* W = (z == 0) ? Wq : (z == 1) ? Wk : (z == 2) ? Wv : (z == 3) ? Wg : Wo;
    int n0 = blockIdx.x * 32, k0 = blockIdx.y * 32;
    int tx = threadIdx.x, ty = threadIdx.y;           // (32, 8)
    #pragma unroll
    for (int j = 0; j < 32; j += 8)
        tile[ty + j][tx] = W[(size_t)(k0 + ty + j) * DMODEL + n0 + tx];
    __syncthreads();
    ushort* o = wt + (size_t)z * DMODEL * DMODEL;
    #pragma unroll
    for (int j = 0; j < 32; j += 8)
        o[(size_t)(n0 + ty + j) * DMODEL + k0 + tx] = f2bf(tile[tx][ty + j]);
}

// ---------------- beta = sigmoid(x @ Wb), fp32 exact ----------------
__global__ void gdn_beta(const float* __restrict__ x, const float* __restrict__ Wb,
                         float* __restrict__ beta) {
    int h = threadIdx.x & 15, mi = threadIdx.x >> 4;
    int m = blockIdx.x * 16 + mi;
    const float* xr = x + (size_t)m * DMODEL;
    float acc = 0.f;
    for (int k = 0; k < DMODEL; ++k)
        acc += xr[k] * Wb[k * NH + h];
    beta[m * NH + h] = 1.f / (1.f + __expf(-acc));
}

// ---------------- bf16 MFMA GEMM: out[M][ldOut] = A[M][1024] * Bt[N][1024]^T ----------------
#define LDT 40
__global__ __launch_bounds__(256) void gdn_gemm(const ushort* __restrict__ A,
                                                const ushort* __restrict__ Bt,
                                                float* __restrict__ outF,
                                                int ldOut) {
    __shared__ ushort As[128 * LDT];
    __shared__ ushort Bs[128 * LDT];
    int tid = threadIdx.x;
    int lane = tid & 63, wid = tid >> 6;
    int wm = wid & 1, wn = wid >> 1;
    int l15 = lane & 15, quad = lane >> 4;
    int bm = blockIdx.x, bn = blockIdx.y;
    const int K = DMODEL;

    f32x4 acc[4][4];
    #pragma unroll
    for (int i = 0; i < 4; i++)
        #pragma unroll
        for (int j = 0; j < 4; j++)
            acc[i][j] = (f32x4){0.f, 0.f, 0.f, 0.f};

    for (int kt = 0; kt < K; kt += 32) {
        __syncthreads();
        #pragma unroll
        for (int i = 0; i < 2; i++) {
            int ch = tid * 2 + i;
            int row = ch >> 2, q = ch & 3;
            uint4 av = ((const uint4*)A)[((bm * 128 + row) * K + kt) / 8 + q];
            *(uint4*)&As[row * LDT + q * 8] = av;
            uint4 bv = ((const uint4*)Bt)[((bn * 128 + row) * K + kt) / 8 + q];
            *(uint4*)&Bs[row * LDT + q * 8] = bv;
        }
        __syncthreads();
        short8 af[4], bf[4];
        #pragma unroll
        for (int i = 0; i < 4; i++) {
            af[i] = *(const short8*)&As[(wm * 64 + i * 16 + l15) * LDT + quad * 8];
            bf[i] = *(const short8*)&Bs[(wn * 64 + i * 16 + l15) * LDT + quad * 8];
        }
        #pragma unroll
        for (int mt = 0; mt < 4; mt++)
            #pragma unroll
            for (int nt = 0; nt < 4; nt++)
                acc[mt][nt] = __builtin_amdgcn_mfma_f32_16x16x32_bf16(
                    af[mt], bf[nt], acc[mt][nt], 0, 0, 0);
    }

    #pragma unroll
    for (int mt = 0; mt < 4; mt++)
        #pragma unroll
        for (int nt = 0; nt < 4; nt++)
            #pragma unroll
            for (int r = 0; r < 4; r++) {
                int row = bm * 128 + wm * 64 + mt * 16 + quad * 4 + r;
                int col = bn * 128 + wn * 64 + nt * 16 + l15;
                outF[(size_t)row * ldOut + col] = acc[mt][nt][r];
            }
}

// ---------------- causal depthwise conv(k=4) + silu (+ l2norm for q/k, q/=8) ----------------
__global__ void gdn_conv(const float* __restrict__ pre,
                         const float* __restrict__ cqw, const float* __restrict__ cqb,
                         const float* __restrict__ ckw, const float* __restrict__ ckb,
                         const float* __restrict__ cvw, const float* __restrict__ cvb,
                         float* __restrict__ qn, float* __restrict__ kn, float* __restrict__ vn) {
    int m = blockIdx.x;
    int which = blockIdx.y;        // 0:q 1:k 2:v
    int t = m & (TSEQ - 1);
    const float* cw = (which == 0) ? cqw : (which == 1) ? ckw : cvw;
    const float* cb = (which == 0) ? cqb : (which == 1) ? ckb : cvb;
    float* dst = (which == 0) ? qn : (which == 1) ? kn : vn;
    int c = threadIdx.x * 4;       // 4 consecutive channels

    float w[4][4];
    #pragma unroll
    for (int i = 0; i < 4; i++) {
        float4 t4 = ((const float4*)cw)[c + i];   // taps of channel c+i
        w[i][0] = t4.x; w[i][1] = t4.y; w[i][2] = t4.z; w[i][3] = t4.w;
    }
    float4 bias = ((const float4*)cb)[threadIdx.x];
    float y[4] = {bias.x, bias.y, bias.z, bias.w};

    const float* src = pre + (size_t)m * 4096 + which * 1024 + c;
    #pragma unroll
    for (int j = 0; j < 4; j++) {
        int tt = t - 3 + j;
        if (tt >= 0) {
            float4 xv = *(const float4*)(src + (long)(j - 3) * 4096);
            y[0] += xv.x * w[0][j];
            y[1] += xv.y * w[1][j];
            y[2] += xv.z * w[2][j];
            y[3] += xv.w * w[3][j];
        }
    }
    #pragma unroll
    for (int i = 0; i < 4; i++) y[i] = silu_f(y[i]);

    if (which < 2) {   // l2norm over 64-channel head groups (16 consecutive lanes)
        float ss = y[0]*y[0] + y[1]*y[1] + y[2]*y[2] + y[3]*y[3];
        ss += __shfl_xor(ss, 1);
        ss += __shfl_xor(ss, 2);
        ss += __shfl_xor(ss, 4);
        ss += __shfl_xor(ss, 8);
        float sc = rsqrtf(ss + 1e-6f);
        if (which == 0) sc *= 0.125f;   // q /= sqrt(d)
        #pragma unroll
        for (int i = 0; i < 4; i++) y[i] *= sc;
    }
    float4 o; o.x = y[0]; o.y = y[1]; o.z = y[2]; o.w = y[3];
    ((float4*)(dst + (size_t)m * 1024))[threadIdx.x] = o;
}

// ---------------- delta-rule recurrence ----------------
// grid: 64 blocks = (b, h, column-half); 64 threads; lane owns 32 rows of one column.
__global__ __launch_bounds__(64) void gdn_recur(const float* __restrict__ qn,
                                                const float* __restrict__ kn,
                                                const float* __restrict__ vn,
                                                const float* __restrict__ beta,
                                                float* __restrict__ otmp) {
    int blk = blockIdx.x;
    int half = blk & 1;
    int h = (blk >> 1) & 15;
    int b = blk >> 5;
    int lane = threadIdx.x;
    int vl = lane & 31;      // column within half
    int rg = lane >> 5;      // row group (0: rows 0..31, 1: rows 32..63)

    float S[32];
    #pragma unroll
    for (int i = 0; i < 32; i++) S[i] = 0.f;

    size_t base = (size_t)b * TSEQ * 1024 + h * 64;
    int bbase = b * TSEQ * NH + h;
    int vofs = half * 32 + vl;

    for (int t = 0; t < TSEQ; ++t) {
        const float4* kp = (const float4*)(kn + base + rg * 32);
        const float4* qp = (const float4*)(qn + base + rg * 32);
        float4 kf[8], qf[8];
        #pragma unroll
        for (int i = 0; i < 8; i++) { kf[i] = kp[i]; qf[i] = qp[i]; }
        float vv = vn[base + vofs];
        float bt = beta[bbase + t * NH];

        float p0 = 0.f, p1 = 0.f, p2 = 0.f, p3 = 0.f;
        #pragma unroll
        for (int i = 0; i < 8; i++) {
            p0 += kf[i].x * S[4*i+0];
            p1 += kf[i].y * S[4*i+1];
            p2 += kf[i].z * S[4*i+2];
            p3 += kf[i].w * S[4*i+3];
        }
        float pk = (p0 + p1) + (p2 + p3);
        pk += __shfl_xor(pk, 32);
        float err = (vv - pk) * bt;

        float q0 = 0.f, q1 = 0.f, q2 = 0.f, q3 = 0.f;
        #pragma unroll
        for (int i = 0; i < 8; i++) {
            S[4*i+0] += kf[i].x * err;
            S[4*i+1] += kf[i].y * err;
            S[4*i+2] += kf[i].z * err;
            S[4*i+3] += kf[i].w * err;
            q0 += qf[i].x * S[4*i+0];
            q1 += qf[i].y * S[4*i+1];
            q2 += qf[i].z * S[4*i+2];
            q3 += qf[i].w * S[4*i+3];
        }
        float pq = (q0 + q1) + (q2 + q3);
        pq += __shfl_xor(pq, 32);
        if (rg == 0) otmp[base + vofs] = pq;
        base += 1024;
    }
}

// ---------------- RMSNorm * nw * silu(gate) -> bf16 ----------------
__global__ void gdn_fuse(const float* __restrict__ otmp, const float* __restrict__ pre,
                         const float* __restrict__ nw, ushort* __restrict__ ofused) {
    int m = blockIdx.x;
    float4 o = ((const float4*)(otmp + (size_t)m * 1024))[threadIdx.x];
    float ss = o.x*o.x + o.y*o.y + o.z*o.z + o.w*o.w;
    ss += __shfl_xor(ss, 1);
    ss += __shfl_xor(ss, 2);
    ss += __shfl_xor(ss, 4);
    ss += __shfl_xor(ss, 8);
    float r = rsqrtf(ss * (1.f / 64.f) + 1e-5f);
    float4 nwv = ((const float4*)nw)[threadIdx.x & 15];
    float4 g = ((const float4*)(pre + (size_t)m * 4096 + 3072))[threadIdx.x];
    ushort4 out;
    out.x = f2bf(o.x * r * nwv.x * silu_f(g.x));
    out.y = f2bf(o.y * r * nwv.y * silu_f(g.y));
    out.z = f2bf(o.z * r * nwv.z * silu_f(g.z));
    out.w = f2bf(o.w * r * nwv.w * silu_f(g.w));
    ((ushort4*)ofused)[m * 256 + threadIdx.x] = out;
}

extern "C" void kernel_launch(void* const* d_in, const int* in_sizes, int n_in,
                              void* d_out, int out_size, void* d_ws, size_t ws_size,
                              hipStream_t stream) {
    const float* x    = (const float*)d_in[0];
    const float* Wq   = (const float*)d_in[1];
    const float* Wk   = (const float*)d_in[2];
    const float* Wv   = (const float*)d_in[3];
    const float* Wo   = (const float*)d_in[4];
    const float* Wg   = (const float*)d_in[5];
    const float* Wb   = (const float*)d_in[6];
    const float* cq_w = (const float*)d_in[7];
    const float* cq_b = (const float*)d_in[8];
    const float* ck_w = (const float*)d_in[9];
    const float* ck_b = (const float*)d_in[10];
    const float* cv_w = (const float*)d_in[11];
    const float* cv_b = (const float*)d_in[12];
    const float* nw   = (const float*)d_in[13];

    char* ws = (char*)d_ws;
    ushort* xb     = (ushort*)(ws);                       // 8 MB
    ushort* wt     = (ushort*)(ws + 8388608);             // 10 MB (5 transposed bf16 weights)
    float*  pre    = (float*)(ws + 18874368);             // 64 MB  [4096][4096] q|k|v|g
    float*  qn     = (float*)(ws + 85983232);             // 16 MB
    float*  kn     = (float*)(ws + 102760448);            // 16 MB
    float*  vn     = (float*)(ws + 119537664);            // 16 MB
    float*  beta   = (float*)(ws + 136314880);            // 256 KB
    float*  otmp   = (float*)(ws + 136577024);            // 16 MB
    ushort* ofused = (ushort*)(ws + 153354240);           // 8 MB  (total ~161.4 MB)

    // 1. x -> bf16
    gdn_cvt_x<<<4096, 256, 0, stream>>>(x, xb);
    // 2. transpose+convert 5 weights
    gdn_cvt_w<<<dim3(32, 32, 5), dim3(32, 8), 0, stream>>>(Wq, Wk, Wv, Wg, Wo, wt);
    // 3. beta (fp32 exact)
    gdn_beta<<<256, 256, 0, stream>>>(x, Wb, beta);
    // 4. fused q/k/v/g pre-activation GEMM: [4096][4096] fp32
    gdn_gemm<<<dim3(32, 32), 256, 0, stream>>>(xb, wt, pre, 4096);
    // 5. conv + silu (+ l2norm)
    gdn_conv<<<dim3(4096, 3), 256, 0, stream>>>(pre, cq_w, cq_b, ck_w, ck_b, cv_w, cv_b,
                                                qn, kn, vn);
    // 6. delta-rule recurrence
    gdn_recur<<<64, 64, 0, stream>>>(qn, kn, vn, beta, otmp);
    // 7. RMSNorm * nw * silu(gate) -> bf16
    gdn_fuse<<<4096, 256, 0, stream>>>(otmp, pre, nw, ofused);
    // 8. final GEMM -> d_out (FP32 — reference output dtype is float32!)
    gdn_gemm<<<dim3(32, 8), 256, 0, stream>>>(ofused, wt + 4 * 1024 * 1024,
                                              (float*)d_out, 1024);
}

// Round 4
// 1408.726 us; speedup vs baseline: 1.0896x; 1.0896x over previous
//
#include <hip/hip_runtime.h>
#include <hip/hip_bf16.h>

typedef __attribute__((ext_vector_type(8))) short short8;
typedef __attribute__((ext_vector_type(4))) float f32x4;

#define TSEQ 2048
#define DMODEL 1024
#define NH 16
#define HD 64

__device__ __forceinline__ ushort f2bf(float f) {
    union { float f; unsigned int u; } c; c.f = f;
    unsigned int u = c.u + 0x7fffu + ((c.u >> 16) & 1u);   // RNE
    return (ushort)(u >> 16);
}

__device__ __forceinline__ float silu_f(float y) {
    return y / (1.f + __expf(-y));
}

// ---------------- convert x -> bf16 ----------------
__global__ void gdn_cvt_x(const float* __restrict__ x, ushort* __restrict__ xb) {
    int i = blockIdx.x * 256 + threadIdx.x;           // one float4 per thread
    float4 v = ((const float4*)x)[i];
    ushort4 o;
    o.x = f2bf(v.x); o.y = f2bf(v.y); o.z = f2bf(v.z); o.w = f2bf(v.w);
    ((ushort4*)xb)[i] = o;
}

// ------------- transpose+convert weights: W[k][n] f32 -> wt[z][n][k] bf16 -------------
__global__ void gdn_cvt_w(const float* __restrict__ Wq, const float* __restrict__ Wk,
                          const float* __restrict__ Wv, const float* __restrict__ Wg,
                          const float* __restrict__ Wo, ushort* __restrict__ wt) {
    __shared__ float tile[32][33];
    int z = blockIdx.z;
    const float* W = (z == 0) ? Wq : (z == 1) ? Wk : (z == 2) ? Wv : (z == 3) ? Wg : Wo;
    int n0 = blockIdx.x * 32, k0 = blockIdx.y * 32;
    int tx = threadIdx.x, ty = threadIdx.y;           // (32, 8)
    #pragma unroll
    for (int j = 0; j < 32; j += 8)
        tile[ty + j][tx] = W[(size_t)(k0 + ty + j) * DMODEL + n0 + tx];
    __syncthreads();
    ushort* o = wt + (size_t)z * DMODEL * DMODEL;
    #pragma unroll
    for (int j = 0; j < 32; j += 8)
        o[(size_t)(n0 + ty + j) * DMODEL + k0 + tx] = f2bf(tile[tx][ty + j]);
}

// ---------------- beta = sigmoid(x @ Wb), fp32 exact ----------------
__global__ void gdn_beta(const float* __restrict__ x, const float* __restrict__ Wb,
                         float* __restrict__ beta) {
    int h = threadIdx.x & 15, mi = threadIdx.x >> 4;
    int m = blockIdx.x * 16 + mi;
    const float* xr = x + (size_t)m * DMODEL;
    float acc = 0.f;
    for (int k = 0; k < DMODEL; ++k)
        acc += xr[k] * Wb[k * NH + h];
    beta[m * NH + h] = 1.f / (1.f + __expf(-acc));
}

// ---------------- bf16 MFMA GEMM: out[M][ldOut] = A[M][1024] * Bt[N][1024]^T ----------------
#define LDT 40
__global__ __launch_bounds__(256) void gdn_gemm(const ushort* __restrict__ A,
                                                const ushort* __restrict__ Bt,
                                                float* __restrict__ outF,
                                                int ldOut) {
    __shared__ ushort As[128 * LDT];
    __shared__ ushort Bs[128 * LDT];
    int tid = threadIdx.x;
    int lane = tid & 63, wid = tid >> 6;
    int wm = wid & 1, wn = wid >> 1;
    int l15 = lane & 15, quad = lane >> 4;
    int bm = blockIdx.x, bn = blockIdx.y;
    const int K = DMODEL;

    f32x4 acc[4][4];
    #pragma unroll
    for (int i = 0; i < 4; i++)
        #pragma unroll
        for (int j = 0; j < 4; j++)
            acc[i][j] = (f32x4){0.f, 0.f, 0.f, 0.f};

    for (int kt = 0; kt < K; kt += 32) {
        __syncthreads();
        #pragma unroll
        for (int i = 0; i < 2; i++) {
            int ch = tid * 2 + i;
            int row = ch >> 2, q = ch & 3;
            uint4 av = ((const uint4*)A)[((bm * 128 + row) * K + kt) / 8 + q];
            *(uint4*)&As[row * LDT + q * 8] = av;
            uint4 bv = ((const uint4*)Bt)[((bn * 128 + row) * K + kt) / 8 + q];
            *(uint4*)&Bs[row * LDT + q * 8] = bv;
        }
        __syncthreads();
        short8 af[4], bf[4];
        #pragma unroll
        for (int i = 0; i < 4; i++) {
            af[i] = *(const short8*)&As[(wm * 64 + i * 16 + l15) * LDT + quad * 8];
            bf[i] = *(const short8*)&Bs[(wn * 64 + i * 16 + l15) * LDT + quad * 8];
        }
        #pragma unroll
        for (int mt = 0; mt < 4; mt++)
            #pragma unroll
            for (int nt = 0; nt < 4; nt++)
                acc[mt][nt] = __builtin_amdgcn_mfma_f32_16x16x32_bf16(
                    af[mt], bf[nt], acc[mt][nt], 0, 0, 0);
    }

    #pragma unroll
    for (int mt = 0; mt < 4; mt++)
        #pragma unroll
        for (int nt = 0; nt < 4; nt++)
            #pragma unroll
            for (int r = 0; r < 4; r++) {
                int row = bm * 128 + wm * 64 + mt * 16 + quad * 4 + r;
                int col = bn * 128 + wn * 64 + nt * 16 + l15;
                outF[(size_t)row * ldOut + col] = acc[mt][nt][r];
            }
}

// ---------------- causal depthwise conv(k=4) + silu (+ l2norm for q/k, q/=8) ----------------
__global__ void gdn_conv(const float* __restrict__ pre,
                         const float* __restrict__ cqw, const float* __restrict__ cqb,
                         const float* __restrict__ ckw, const float* __restrict__ ckb,
                         const float* __restrict__ cvw, const float* __restrict__ cvb,
                         float* __restrict__ qn, float* __restrict__ kn, float* __restrict__ vn) {
    int m = blockIdx.x;
    int which = blockIdx.y;        // 0:q 1:k 2:v
    int t = m & (TSEQ - 1);
    const float* cw = (which == 0) ? cqw : (which == 1) ? ckw : cvw;
    const float* cb = (which == 0) ? cqb : (which == 1) ? ckb : cvb;
    float* dst = (which == 0) ? qn : (which == 1) ? kn : vn;
    int c = threadIdx.x * 4;       // 4 consecutive channels

    float w[4][4];
    #pragma unroll
    for (int i = 0; i < 4; i++) {
        float4 t4 = ((const float4*)cw)[c + i];   // taps of channel c+i
        w[i][0] = t4.x; w[i][1] = t4.y; w[i][2] = t4.z; w[i][3] = t4.w;
    }
    float4 bias = ((const float4*)cb)[threadIdx.x];
    float y[4] = {bias.x, bias.y, bias.z, bias.w};

    const float* src = pre + (size_t)m * 4096 + which * 1024 + c;
    #pragma unroll
    for (int j = 0; j < 4; j++) {
        int tt = t - 3 + j;
        if (tt >= 0) {
            float4 xv = *(const float4*)(src + (long)(j - 3) * 4096);
            y[0] += xv.x * w[0][j];
            y[1] += xv.y * w[1][j];
            y[2] += xv.z * w[2][j];
            y[3] += xv.w * w[3][j];
        }
    }
    #pragma unroll
    for (int i = 0; i < 4; i++) y[i] = silu_f(y[i]);

    if (which < 2) {   // l2norm over 64-channel head groups (16 consecutive lanes)
        float ss = y[0]*y[0] + y[1]*y[1] + y[2]*y[2] + y[3]*y[3];
        ss += __shfl_xor(ss, 1);
        ss += __shfl_xor(ss, 2);
        ss += __shfl_xor(ss, 4);
        ss += __shfl_xor(ss, 8);
        float sc = rsqrtf(ss + 1e-6f);
        if (which == 0) sc *= 0.125f;   // q /= sqrt(d)
        #pragma unroll
        for (int i = 0; i < 4; i++) y[i] *= sc;
    }
    float4 o; o.x = y[0]; o.y = y[1]; o.z = y[2]; o.w = y[3];
    ((float4*)(dst + (size_t)m * 1024))[threadIdx.x] = o;
}

// ---------------- delta-rule recurrence, chunked LDS pipeline ----------------
// grid: 64 blocks = (b, h, column-half); 64 threads; lane owns 32 rows of one column.
// Chunks of RC=16 steps: prefetch chunk c+1 into registers (coalesced), compute chunk c
// from LDS, then commit regs->LDS (wave-synchronous, no barrier needed).
#define RC 16
__global__ __launch_bounds__(64) void gdn_recur(const float* __restrict__ qn,
                                                const float* __restrict__ kn,
                                                const float* __restrict__ vn,
                                                const float* __restrict__ beta,
                                                float* __restrict__ otmp) {
    __shared__ float k_lds[RC][64];
    __shared__ float q_lds[RC][64];
    __shared__ float v_lds[RC][32];

    int blk = blockIdx.x;
    int half = blk & 1;
    int h = (blk >> 1) & 15;
    int b = blk >> 5;
    int lane = threadIdx.x;
    int vl = lane & 31;      // column within half
    int rg = lane >> 5;      // row group (0: rows 0..31, 1: rows 32..63)

    float S[32];
    #pragma unroll
    for (int i = 0; i < 32; i++) S[i] = 0.f;

    size_t base0 = (size_t)b * TSEQ * 1024 + h * 64;  // + t*1024 per step
    int bbase = b * TSEQ * NH + h;

    // cooperative chunk staging: k/q 4 float4/lane, v 2 float4/lane
    int kq_s  = (lane >> 4);        // step sub-index contribution (i*4 + this)
    int kq_c  = (lane & 15) * 4;    // float offset within 64-float row
    int v_s   = (lane >> 3);
    int v_c   = (lane & 7) * 4;

    float4 pk[4], pq[4], pv[2];

    #define ISSUE_LOADS(T0)                                                          \
        {                                                                            \
            _Pragma("unroll")                                                        \
            for (int i = 0; i < 4; i++) {                                            \
                int s = i * 4 + kq_s;                                                \
                pk[i] = *(const float4*)(kn + base0 + (size_t)((T0) + s) * 1024 + kq_c); \
                pq[i] = *(const float4*)(qn + base0 + (size_t)((T0) + s) * 1024 + kq_c); \
            }                                                                        \
            _Pragma("unroll")                                                        \
            for (int i = 0; i < 2; i++) {                                            \
                int s = i * 8 + v_s;                                                 \
                pv[i] = *(const float4*)(vn + base0 + (size_t)((T0) + s) * 1024      \
                                         + half * 32 + v_c);                         \
            }                                                                        \
        }

    #define COMMIT_LDS()                                                             \
        {                                                                            \
            _Pragma("unroll")                                                        \
            for (int i = 0; i < 4; i++) {                                            \
                int s = i * 4 + kq_s;                                                \
                *(float4*)&k_lds[s][kq_c] = pk[i];                                   \
                *(float4*)&q_lds[s][kq_c] = pq[i];                                   \
            }                                                                        \
            _Pragma("unroll")                                                        \
            for (int i = 0; i < 2; i++) {                                            \
                int s = i * 8 + v_s;                                                 \
                *(float4*)&v_lds[s][v_c] = pv[i];                                    \
            }                                                                        \
        }

    ISSUE_LOADS(0);
    COMMIT_LDS();
    __syncthreads();

    for (int c = 0; c < TSEQ / RC; ++c) {
        int t0n = ((c + 1) < TSEQ / RC) ? (c + 1) * RC : 0;
        ISSUE_LOADS(t0n);          // in flight while we compute this chunk

        #pragma unroll
        for (int t = 0; t < RC; ++t) {
            float4 kf[8], qf[8];
            #pragma unroll
            for (int i = 0; i < 8; i++) {
                kf[i] = *(const float4*)&k_lds[t][rg * 32 + i * 4];
                qf[i] = *(const float4*)&q_lds[t][rg * 32 + i * 4];
            }
            float vv = v_lds[t][vl];
            float bt = beta[bbase + (c * RC + t) * NH];

            float p0 = 0.f, p1 = 0.f, p2 = 0.f, p3 = 0.f;
            #pragma unroll
            for (int i = 0; i < 8; i++) {
                p0 += kf[i].x * S[4*i+0];
                p1 += kf[i].y * S[4*i+1];
                p2 += kf[i].z * S[4*i+2];
                p3 += kf[i].w * S[4*i+3];
            }
            float pk_ = (p0 + p1) + (p2 + p3);
            pk_ += __shfl_xor(pk_, 32);
            float err = (vv - pk_) * bt;

            float q0 = 0.f, q1 = 0.f, q2 = 0.f, q3 = 0.f;
            #pragma unroll
            for (int i = 0; i < 8; i++) {
                S[4*i+0] += kf[i].x * err;
                S[4*i+1] += kf[i].y * err;
                S[4*i+2] += kf[i].z * err;
                S[4*i+3] += kf[i].w * err;
                q0 += qf[i].x * S[4*i+0];
                q1 += qf[i].y * S[4*i+1];
                q2 += qf[i].z * S[4*i+2];
                q3 += qf[i].w * S[4*i+3];
            }
            float pq_ = (q0 + q1) + (q2 + q3);
            pq_ += __shfl_xor(pq_, 32);
            if (rg == 0)
                otmp[base0 + (size_t)(c * RC + t) * 1024 + half * 32 + vl] = pq_;
        }
        // wave-synchronous: all lanes finished reading this chunk's LDS in program
        // order; safe to overwrite (same-array aliasing keeps compiler ordering).
        COMMIT_LDS();
    }
}

// ---------------- RMSNorm * nw * silu(gate) -> bf16 ----------------
__global__ void gdn_fuse(const float* __restrict__ otmp, const float* __restrict__ pre,
                         const float* __restrict__ nw, ushort* __restrict__ ofused) {
    int m = blockIdx.x;
    float4 o = ((const float4*)(otmp + (size_t)m * 1024))[threadIdx.x];
    float ss = o.x*o.x + o.y*o.y + o.z*o.z + o.w*o.w;
    ss += __shfl_xor(ss, 1);
    ss += __shfl_xor(ss, 2);
    ss += __shfl_xor(ss, 4);
    ss += __shfl_xor(ss, 8);
    float r = rsqrtf(ss * (1.f / 64.f) + 1e-5f);
    float4 nwv = ((const float4*)nw)[threadIdx.x & 15];
    float4 g = ((const float4*)(pre + (size_t)m * 4096 + 3072))[threadIdx.x];
    ushort4 out;
    out.x = f2bf(o.x * r * nwv.x * silu_f(g.x));
    out.y = f2bf(o.y * r * nwv.y * silu_f(g.y));
    out.z = f2bf(o.z * r * nwv.z * silu_f(g.z));
    out.w = f2bf(o.w * r * nwv.w * silu_f(g.w));
    ((ushort4*)ofused)[m * 256 + threadIdx.x] = out;
}

extern "C" void kernel_launch(void* const* d_in, const int* in_sizes, int n_in,
                              void* d_out, int out_size, void* d_ws, size_t ws_size,
                              hipStream_t stream) {
    const float* x    = (const float*)d_in[0];
    const float* Wq   = (const float*)d_in[1];
    const float* Wk   = (const float*)d_in[2];
    const float* Wv   = (const float*)d_in[3];
    const float* Wo   = (const float*)d_in[4];
    const float* Wg   = (const float*)d_in[5];
    const float* Wb   = (const float*)d_in[6];
    const float* cq_w = (const float*)d_in[7];
    const float* cq_b = (const float*)d_in[8];
    const float* ck_w = (const float*)d_in[9];
    const float* ck_b = (const float*)d_in[10];
    const float* cv_w = (const float*)d_in[11];
    const float* cv_b = (const float*)d_in[12];
    const float* nw   = (const float*)d_in[13];

    char* ws = (char*)d_ws;
    ushort* xb     = (ushort*)(ws);                       // 8 MB
    ushort* wt     = (ushort*)(ws + 8388608);             // 10 MB (5 transposed bf16 weights)
    float*  pre    = (float*)(ws + 18874368);             // 64 MB  [4096][4096] q|k|v|g
    float*  qn     = (float*)(ws + 85983232);             // 16 MB
    float*  kn     = (float*)(ws + 102760448);            // 16 MB
    float*  vn     = (float*)(ws + 119537664);            // 16 MB
    float*  beta   = (float*)(ws + 136314880);            // 256 KB
    float*  otmp   = (float*)(ws + 136577024);            // 16 MB
    ushort* ofused = (ushort*)(ws + 153354240);           // 8 MB  (total ~161.4 MB)

    // 1. x -> bf16
    gdn_cvt_x<<<4096, 256, 0, stream>>>(x, xb);
    // 2. transpose+convert 5 weights
    gdn_cvt_w<<<dim3(32, 32, 5), dim3(32, 8), 0, stream>>>(Wq, Wk, Wv, Wg, Wo, wt);
    // 3. beta (fp32 exact)
    gdn_beta<<<256, 256, 0, stream>>>(x, Wb, beta);
    // 4. fused q/k/v/g pre-activation GEMM: [4096][4096] fp32
    gdn_gemm<<<dim3(32, 32), 256, 0, stream>>>(xb, wt, pre, 4096);
    // 5. conv + silu (+ l2norm)
    gdn_conv<<<dim3(4096, 3), 256, 0, stream>>>(pre, cq_w, cq_b, ck_w, ck_b, cv_w, cv_b,
                                                qn, kn, vn);
    // 6. delta-rule recurrence (chunked LDS pipeline)
    gdn_recur<<<64, 64, 0, stream>>>(qn, kn, vn, beta, otmp);
    // 7. RMSNorm * nw * silu(gate) -> bf16
    gdn_fuse<<<4096, 256, 0, stream>>>(otmp, pre, nw, ofused);
    // 8. final GEMM -> d_out (fp32 output)
    gdn_gemm<<<dim3(32, 8), 256, 0, stream>>>(ofused, wt + 4 * 1024 * 1024,
                                              (float*)d_out, 1024);
}

// Round 5
// 759.129 us; speedup vs baseline: 2.0219x; 1.8557x over previous
//
#include <hip/hip_runtime.h>
#include <hip/hip_bf16.h>

typedef __attribute__((ext_vector_type(8))) short short8;
typedef __attribute__((ext_vector_type(4))) float f32x4;

#define TSEQ 2048
#define DMODEL 1024
#define NH 16
#define HD 64

__device__ __forceinline__ ushort f2bf(float f) {
    union { float f; unsigned int u; } c; c.f = f;
    unsigned int u = c.u + 0x7fffu + ((c.u >> 16) & 1u);   // RNE
    return (ushort)(u >> 16);
}

__device__ __forceinline__ float silu_f(float y) {
    return y / (1.f + __expf(-y));
}

// quad_perm DPP butterflies: xor1 = [1,0,3,2] = 0xB1, xor2 = [2,3,0,1] = 0x4E
__device__ __forceinline__ float dpp_xor1(float x) {
    return __int_as_float(__builtin_amdgcn_update_dpp(
        0, __float_as_int(x), 0xB1, 0xF, 0xF, true));
}
__device__ __forceinline__ float dpp_xor2(float x) {
    return __int_as_float(__builtin_amdgcn_update_dpp(
        0, __float_as_int(x), 0x4E, 0xF, 0xF, true));
}

// ---------------- convert x -> bf16 ----------------
__global__ void gdn_cvt_x(const float* __restrict__ x, ushort* __restrict__ xb) {
    int i = blockIdx.x * 256 + threadIdx.x;           // one float4 per thread
    float4 v = ((const float4*)x)[i];
    ushort4 o;
    o.x = f2bf(v.x); o.y = f2bf(v.y); o.z = f2bf(v.z); o.w = f2bf(v.w);
    ((ushort4*)xb)[i] = o;
}

// ------------- transpose+convert weights: W[k][n] f32 -> wt[z][n][k] bf16 -------------
__global__ void gdn_cvt_w(const float* __restrict__ Wq, const float* __restrict__ Wk,
                          const float* __restrict__ Wv, const float* __restrict__ Wg,
                          const float* __restrict__ Wo, ushort* __restrict__ wt) {
    __shared__ float tile[32][33];
    int z = blockIdx.z;
    const float* W = (z == 0) ? Wq : (z == 1) ? Wk : (z == 2) ? Wv : (z == 3) ? Wg : Wo;
    int n0 = blockIdx.x * 32, k0 = blockIdx.y * 32;
    int tx = threadIdx.x, ty = threadIdx.y;           // (32, 8)
    #pragma unroll
    for (int j = 0; j < 32; j += 8)
        tile[ty + j][tx] = W[(size_t)(k0 + ty + j) * DMODEL + n0 + tx];
    __syncthreads();
    ushort* o = wt + (size_t)z * DMODEL * DMODEL;
    #pragma unroll
    for (int j = 0; j < 32; j += 8)
        o[(size_t)(n0 + ty + j) * DMODEL + k0 + tx] = f2bf(tile[tx][ty + j]);
}

// ---------------- betaT[(b*NH+h)*TSEQ + t] = sigmoid(x @ Wb), fp32 exact ----------------
__global__ void gdn_beta(const float* __restrict__ x, const float* __restrict__ Wb,
                         float* __restrict__ betaT) {
    int h = threadIdx.x & 15, mi = threadIdx.x >> 4;
    int m = blockIdx.x * 16 + mi;
    const float* xr = x + (size_t)m * DMODEL;
    float acc = 0.f;
    for (int k = 0; k < DMODEL; ++k)
        acc += xr[k] * Wb[k * NH + h];
    int b = m >> 11, t = m & (TSEQ - 1);
    betaT[((b * NH + h) << 11) + t] = 1.f / (1.f + __expf(-acc));
}

// ---------------- bf16 MFMA GEMM: out[M][ldOut] = A[M][1024] * Bt[N][1024]^T ----------------
#define LDT 40
__global__ __launch_bounds__(256) void gdn_gemm(const ushort* __restrict__ A,
                                                const ushort* __restrict__ Bt,
                                                float* __restrict__ outF,
                                                int ldOut) {
    __shared__ ushort As[128 * LDT];
    __shared__ ushort Bs[128 * LDT];
    int tid = threadIdx.x;
    int lane = tid & 63, wid = tid >> 6;
    int wm = wid & 1, wn = wid >> 1;
    int l15 = lane & 15, quad = lane >> 4;
    int bm = blockIdx.x, bn = blockIdx.y;
    const int K = DMODEL;

    f32x4 acc[4][4];
    #pragma unroll
    for (int i = 0; i < 4; i++)
        #pragma unroll
        for (int j = 0; j < 4; j++)
            acc[i][j] = (f32x4){0.f, 0.f, 0.f, 0.f};

    for (int kt = 0; kt < K; kt += 32) {
        __syncthreads();
        #pragma unroll
        for (int i = 0; i < 2; i++) {
            int ch = tid * 2 + i;
            int row = ch >> 2, q = ch & 3;
            uint4 av = ((const uint4*)A)[((bm * 128 + row) * K + kt) / 8 + q];
            *(uint4*)&As[row * LDT + q * 8] = av;
            uint4 bv = ((const uint4*)Bt)[((bn * 128 + row) * K + kt) / 8 + q];
            *(uint4*)&Bs[row * LDT + q * 8] = bv;
        }
        __syncthreads();
        short8 af[4], bf[4];
        #pragma unroll
        for (int i = 0; i < 4; i++) {
            af[i] = *(const short8*)&As[(wm * 64 + i * 16 + l15) * LDT + quad * 8];
            bf[i] = *(const short8*)&Bs[(wn * 64 + i * 16 + l15) * LDT + quad * 8];
        }
        #pragma unroll
        for (int mt = 0; mt < 4; mt++)
            #pragma unroll
            for (int nt = 0; nt < 4; nt++)
                acc[mt][nt] = __builtin_amdgcn_mfma_f32_16x16x32_bf16(
                    af[mt], bf[nt], acc[mt][nt], 0, 0, 0);
    }

    #pragma unroll
    for (int mt = 0; mt < 4; mt++)
        #pragma unroll
        for (int nt = 0; nt < 4; nt++)
            #pragma unroll
            for (int r = 0; r < 4; r++) {
                int row = bm * 128 + wm * 64 + mt * 16 + quad * 4 + r;
                int col = bn * 128 + wn * 64 + nt * 16 + l15;
                outF[(size_t)row * ldOut + col] = acc[mt][nt][r];
            }
}

// ---------------- causal depthwise conv(k=4) + silu (+ l2norm for q/k, q/=8) ----------------
__global__ void gdn_conv(const float* __restrict__ pre,
                         const float* __restrict__ cqw, const float* __restrict__ cqb,
                         const float* __restrict__ ckw, const float* __restrict__ ckb,
                         const float* __restrict__ cvw, const float* __restrict__ cvb,
                         float* __restrict__ qn, float* __restrict__ kn, float* __restrict__ vn) {
    int m = blockIdx.x;
    int which = blockIdx.y;        // 0:q 1:k 2:v
    int t = m & (TSEQ - 1);
    const float* cw = (which == 0) ? cqw : (which == 1) ? ckw : cvw;
    const float* cb = (which == 0) ? cqb : (which == 1) ? ckb : cvb;
    float* dst = (which == 0) ? qn : (which == 1) ? kn : vn;
    int c = threadIdx.x * 4;       // 4 consecutive channels

    float w[4][4];
    #pragma unroll
    for (int i = 0; i < 4; i++) {
        float4 t4 = ((const float4*)cw)[c + i];   // taps of channel c+i
        w[i][0] = t4.x; w[i][1] = t4.y; w[i][2] = t4.z; w[i][3] = t4.w;
    }
    float4 bias = ((const float4*)cb)[threadIdx.x];
    float y[4] = {bias.x, bias.y, bias.z, bias.w};

    const float* src = pre + (size_t)m * 4096 + which * 1024 + c;
    #pragma unroll
    for (int j = 0; j < 4; j++) {
        int tt = t - 3 + j;
        if (tt >= 0) {
            float4 xv = *(const float4*)(src + (long)(j - 3) * 4096);
            y[0] += xv.x * w[0][j];
            y[1] += xv.y * w[1][j];
            y[2] += xv.z * w[2][j];
            y[3] += xv.w * w[3][j];
        }
    }
    #pragma unroll
    for (int i = 0; i < 4; i++) y[i] = silu_f(y[i]);

    if (which < 2) {   // l2norm over 64-channel head groups (16 consecutive lanes)
        float ss = y[0]*y[0] + y[1]*y[1] + y[2]*y[2] + y[3]*y[3];
        ss += __shfl_xor(ss, 1);
        ss += __shfl_xor(ss, 2);
        ss += __shfl_xor(ss, 4);
        ss += __shfl_xor(ss, 8);
        float sc = rsqrtf(ss + 1e-6f);
        if (which == 0) sc *= 0.125f;   // q /= sqrt(d)
        #pragma unroll
        for (int i = 0; i < 4; i++) y[i] *= sc;
    }
    float4 o; o.x = y[0]; o.y = y[1]; o.z = y[2]; o.w = y[3];
    ((float4*)(dst + (size_t)m * 1024))[threadIdx.x] = o;
}

// ---------------- delta-rule recurrence, quad-DPP + LDS chunk pipeline ----------------
// grid: 128 blocks = (b, h, col-quarter); 64 threads (1 wave).
// lane = col16*4 + rg: rg = lane&3 owns rows rg*16..rg*16+15; col16 = lane>>2 (0..15).
// Reductions over the 4 quad lanes via DPP quad_perm (pure VALU).
#define RC 16
__global__ __launch_bounds__(64) void gdn_recur(const float* __restrict__ qn,
                                                const float* __restrict__ kn,
                                                const float* __restrict__ vn,
                                                const float* __restrict__ betaT,
                                                float* __restrict__ otmp) {
    __shared__ float k_lds[RC][64];
    __shared__ float q_lds[RC][64];
    __shared__ float v_lds[RC][16];
    __shared__ float beta_lds[TSEQ];

    int blk = blockIdx.x;
    int cq = blk & 3;
    int h = (blk >> 2) & 15;
    int b = blk >> 6;
    int lane = threadIdx.x;
    int rg = lane & 3;        // row group of 16
    int col16 = lane >> 2;    // column within quarter

    float S[16];
    #pragma unroll
    for (int i = 0; i < 16; i++) S[i] = 0.f;

    size_t base0 = (size_t)b * TSEQ * 1024 + h * 64;

    // preload all betas for this (b,h): coalesced from betaT
    {
        const float* bsrc = betaT + ((size_t)(b * NH + h) << 11);
        #pragma unroll
        for (int i = 0; i < TSEQ / 64; ++i)
            beta_lds[i * 64 + lane] = bsrc[i * 64 + lane];
    }
    __syncthreads();

    // chunk staging: k/q 4 float4/lane, v 1 float4/lane
    int kq_s = lane >> 4;          // step contribution (i*4 + this)
    int kq_c = (lane & 15) * 4;    // float offset within 64-float row
    int v_s  = lane >> 2;          // step 0..15
    int v_c  = (lane & 3) * 4;     // float offset within 16-float row

    float4 pk[4], pq[4], pv;

    #define ISSUE_LOADS(T0)                                                              \
        {                                                                                \
            _Pragma("unroll")                                                            \
            for (int i = 0; i < 4; i++) {                                                \
                int s = i * 4 + kq_s;                                                    \
                pk[i] = *(const float4*)(kn + base0 + (size_t)((T0) + s) * 1024 + kq_c); \
                pq[i] = *(const float4*)(qn + base0 + (size_t)((T0) + s) * 1024 + kq_c); \
            }                                                                            \
            pv = *(const float4*)(vn + base0 + (size_t)((T0) + v_s) * 1024               \
                                  + cq * 16 + v_c);                                      \
        }

    #define COMMIT_LDS()                                                                 \
        {                                                                                \
            _Pragma("unroll")                                                            \
            for (int i = 0; i < 4; i++) {                                                \
                int s = i * 4 + kq_s;                                                    \
                *(float4*)&k_lds[s][kq_c] = pk[i];                                       \
                *(float4*)&q_lds[s][kq_c] = pq[i];                                       \
            }                                                                            \
            *(float4*)&v_lds[v_s][v_c] = pv;                                             \
        }

    ISSUE_LOADS(0);
    COMMIT_LDS();
    __syncthreads();

    for (int c = 0; c < TSEQ / RC; ++c) {
        int t0n = ((c + 1) < TSEQ / RC) ? (c + 1) * RC : 0;
        ISSUE_LOADS(t0n);          // next chunk in flight during compute

        float4 btv[4];             // this chunk's betas (wave-uniform values)
        #pragma unroll
        for (int i = 0; i < 4; i++)
            btv[i] = *(const float4*)&beta_lds[c * RC + i * 4];

        #pragma unroll
        for (int t = 0; t < RC; ++t) {
            float4 kf[4], qf[4];
            #pragma unroll
            for (int i = 0; i < 4; i++) {
                kf[i] = *(const float4*)&k_lds[t][rg * 16 + i * 4];
                qf[i] = *(const float4*)&q_lds[t][rg * 16 + i * 4];
            }
            float vv = v_lds[t][col16];
            float bt = ((const float*)btv)[t];

            float p0 = 0.f, p1 = 0.f, p2 = 0.f, p3 = 0.f;
            #pragma unroll
            for (int i = 0; i < 4; i++) {
                p0 += kf[i].x * S[4*i+0];
                p1 += kf[i].y * S[4*i+1];
                p2 += kf[i].z * S[4*i+2];
                p3 += kf[i].w * S[4*i+3];
            }
            float pk_ = (p0 + p1) + (p2 + p3);
            pk_ += dpp_xor1(pk_);
            pk_ += dpp_xor2(pk_);          // sum over all 64 rows (quad butterfly)
            float err = (vv - pk_) * bt;

            float q0 = 0.f, q1 = 0.f, q2 = 0.f, q3 = 0.f;
            #pragma unroll
            for (int i = 0; i < 4; i++) {
                S[4*i+0] += kf[i].x * err;
                S[4*i+1] += kf[i].y * err;
                S[4*i+2] += kf[i].z * err;
                S[4*i+3] += kf[i].w * err;
                q0 += qf[i].x * S[4*i+0];
                q1 += qf[i].y * S[4*i+1];
                q2 += qf[i].z * S[4*i+2];
                q3 += qf[i].w * S[4*i+3];
            }
            float pq_ = (q0 + q1) + (q2 + q3);
            pq_ += dpp_xor1(pq_);
            pq_ += dpp_xor2(pq_);
            if (rg == 0)
                otmp[base0 + (size_t)(c * RC + t) * 1024 + cq * 16 + col16] = pq_;
        }
        // wave-synchronous: this chunk's LDS reads precede these writes in
        // program order (single wave, in-order DS pipe) — safe to overwrite.
        COMMIT_LDS();
    }
}

// ---------------- RMSNorm * nw * silu(gate) -> bf16 ----------------
__global__ void gdn_fuse(const float* __restrict__ otmp, const float* __restrict__ pre,
                         const float* __restrict__ nw, ushort* __restrict__ ofused) {
    int m = blockIdx.x;
    float4 o = ((const float4*)(otmp + (size_t)m * 1024))[threadIdx.x];
    float ss = o.x*o.x + o.y*o.y + o.z*o.z + o.w*o.w;
    ss += __shfl_xor(ss, 1);
    ss += __shfl_xor(ss, 2);
    ss += __shfl_xor(ss, 4);
    ss += __shfl_xor(ss, 8);
    float r = rsqrtf(ss * (1.f / 64.f) + 1e-5f);
    float4 nwv = ((const float4*)nw)[threadIdx.x & 15];
    float4 g = ((const float4*)(pre + (size_t)m * 4096 + 3072))[threadIdx.x];
    ushort4 out;
    out.x = f2bf(o.x * r * nwv.x * silu_f(g.x));
    out.y = f2bf(o.y * r * nwv.y * silu_f(g.y));
    out.z = f2bf(o.z * r * nwv.z * silu_f(g.z));
    out.w = f2bf(o.w * r * nwv.w * silu_f(g.w));
    ((ushort4*)ofused)[m * 256 + threadIdx.x] = out;
}

extern "C" void kernel_launch(void* const* d_in, const int* in_sizes, int n_in,
                              void* d_out, int out_size, void* d_ws, size_t ws_size,
                              hipStream_t stream) {
    const float* x    = (const float*)d_in[0];
    const float* Wq   = (const float*)d_in[1];
    const float* Wk   = (const float*)d_in[2];
    const float* Wv   = (const float*)d_in[3];
    const float* Wo   = (const float*)d_in[4];
    const float* Wg   = (const float*)d_in[5];
    const float* Wb   = (const float*)d_in[6];
    const float* cq_w = (const float*)d_in[7];
    const float* cq_b = (const float*)d_in[8];
    const float* ck_w = (const float*)d_in[9];
    const float* ck_b = (const float*)d_in[10];
    const float* cv_w = (const float*)d_in[11];
    const float* cv_b = (const float*)d_in[12];
    const float* nw   = (const float*)d_in[13];

    char* ws = (char*)d_ws;
    ushort* xb     = (ushort*)(ws);                       // 8 MB
    ushort* wt     = (ushort*)(ws + 8388608);             // 10 MB (5 transposed bf16 weights)
    float*  pre    = (float*)(ws + 18874368);             // 64 MB  [4096][4096] q|k|v|g
    float*  qn     = (float*)(ws + 85983232);             // 16 MB
    float*  kn     = (float*)(ws + 102760448);            // 16 MB
    float*  vn     = (float*)(ws + 119537664);            // 16 MB
    float*  betaT  = (float*)(ws + 136314880);            // 256 KB
    float*  otmp   = (float*)(ws + 136577024);            // 16 MB
    ushort* ofused = (ushort*)(ws + 153354240);           // 8 MB  (total ~161.4 MB)

    // 1. x -> bf16
    gdn_cvt_x<<<4096, 256, 0, stream>>>(x, xb);
    // 2. transpose+convert 5 weights
    gdn_cvt_w<<<dim3(32, 32, 5), dim3(32, 8), 0, stream>>>(Wq, Wk, Wv, Wg, Wo, wt);
    // 3. betaT (fp32 exact, transposed layout)
    gdn_beta<<<256, 256, 0, stream>>>(x, Wb, betaT);
    // 4. fused q/k/v/g pre-activation GEMM: [4096][4096] fp32
    gdn_gemm<<<dim3(32, 32), 256, 0, stream>>>(xb, wt, pre, 4096);
    // 5. conv + silu (+ l2norm)
    gdn_conv<<<dim3(4096, 3), 256, 0, stream>>>(pre, cq_w, cq_b, ck_w, ck_b, cv_w, cv_b,
                                                qn, kn, vn);
    // 6. delta-rule recurrence (quad-DPP, 128 blocks)
    gdn_recur<<<128, 64, 0, stream>>>(qn, kn, vn, betaT, otmp);
    // 7. RMSNorm * nw * silu(gate) -> bf16
    gdn_fuse<<<4096, 256, 0, stream>>>(otmp, pre, nw, ofused);
    // 8. final GEMM -> d_out (fp32 output)
    gdn_gemm<<<dim3(32, 8), 256, 0, stream>>>(ofused, wt + 4 * 1024 * 1024,
                                              (float*)d_out, 1024);
}

// Round 7
// 547.318 us; speedup vs baseline: 2.8044x; 1.3870x over previous
//
#include <hip/hip_runtime.h>
#include <hip/hip_bf16.h>

typedef __attribute__((ext_vector_type(8))) short short8;
typedef __attribute__((ext_vector_type(4))) float f32x4;

#define TSEQ 2048
#define DMODEL 1024
#define NH 16
#define HD 64

__device__ __forceinline__ ushort f2bf(float f) {
    union { float f; unsigned int u; } c; c.f = f;
    unsigned int u = c.u + 0x7fffu + ((c.u >> 16) & 1u);   // RNE
    return (ushort)(u >> 16);
}

__device__ __forceinline__ float silu_f(float y) {
    return y / (1.f + __expf(-y));
}

// DPP helpers. ctrl must be a constant expression -> template parameter.
template <int CTRL>
__device__ __forceinline__ float dpp_add(float x) {
    return x + __int_as_float(__builtin_amdgcn_update_dpp(
        0, __float_as_int(x), CTRL, 0xF, 0xF, true));
}
// Reduction over a row of 16 lanes (sub-group sums uniform before each later
// stage, so mirror patterns act as butterflies).
__device__ __forceinline__ float red16(float x) {
    x = dpp_add<0xB1>(x);    // quad_perm [1,0,3,2]  (xor 1)
    x = dpp_add<0x4E>(x);    // quad_perm [2,3,0,1]  (xor 2)
    x = dpp_add<0x141>(x);   // row_half_mirror      (combine quads within 8)
    x = dpp_add<0x140>(x);   // row_mirror           (combine 8-groups within 16)
    return x;
}

// async global->LDS (dest = uniform base + lane*size)
__device__ __forceinline__ void gl_lds16(const float* g, float* l) {
    __builtin_amdgcn_global_load_lds(
        (__attribute__((address_space(1))) void*)g,
        (__attribute__((address_space(3))) void*)l, 16, 0, 0);
}
__device__ __forceinline__ void gl_lds4(const float* g, float* l) {
    __builtin_amdgcn_global_load_lds(
        (__attribute__((address_space(1))) void*)g,
        (__attribute__((address_space(3))) void*)l, 4, 0, 0);
}

// ---------------- convert x -> bf16 ----------------
__global__ void gdn_cvt_x(const float* __restrict__ x, ushort* __restrict__ xb) {
    int i = blockIdx.x * 256 + threadIdx.x;           // one float4 per thread
    float4 v = ((const float4*)x)[i];
    ushort4 o;
    o.x = f2bf(v.x); o.y = f2bf(v.y); o.z = f2bf(v.z); o.w = f2bf(v.w);
    ((ushort4*)xb)[i] = o;
}

// ------------- transpose+convert weights: W[k][n] f32 -> wt[z][n][k] bf16 -------------
__global__ void gdn_cvt_w(const float* __restrict__ Wq, const float* __restrict__ Wk,
                          const float* __restrict__ Wv, const float* __restrict__ Wg,
                          const float* __restrict__ Wo, ushort* __restrict__ wt) {
    __shared__ float tile[32][33];
    int z = blockIdx.z;
    const float* W = (z == 0) ? Wq : (z == 1) ? Wk : (z == 2) ? Wv : (z == 3) ? Wg : Wo;
    int n0 = blockIdx.x * 32, k0 = blockIdx.y * 32;
    int tx = threadIdx.x, ty = threadIdx.y;           // (32, 8)
    #pragma unroll
    for (int j = 0; j < 32; j += 8)
        tile[ty + j][tx] = W[(size_t)(k0 + ty + j) * DMODEL + n0 + tx];
    __syncthreads();
    ushort* o = wt + (size_t)z * DMODEL * DMODEL;
    #pragma unroll
    for (int j = 0; j < 32; j += 8)
        o[(size_t)(n0 + ty + j) * DMODEL + k0 + tx] = f2bf(tile[tx][ty + j]);
}

// ---------------- betaT[(b*NH+h)*TSEQ + t] = sigmoid(x @ Wb), fp32 exact ----------------
__global__ void gdn_beta(const float* __restrict__ x, const float* __restrict__ Wb,
                         float* __restrict__ betaT) {
    int h = threadIdx.x & 15, mi = threadIdx.x >> 4;
    int m = blockIdx.x * 16 + mi;
    const float* xr = x + (size_t)m * DMODEL;
    float acc = 0.f;
    for (int k = 0; k < DMODEL; ++k)
        acc += xr[k] * Wb[k * NH + h];
    int b = m >> 11, t = m & (TSEQ - 1);
    betaT[((b * NH + h) << 11) + t] = 1.f / (1.f + __expf(-acc));
}

// ---------------- bf16 MFMA GEMM: out[M][ldOut] = A[M][1024] * Bt[N][1024]^T ----------------
#define LDT 40
__global__ __launch_bounds__(256) void gdn_gemm(const ushort* __restrict__ A,
                                                const ushort* __restrict__ Bt,
                                                float* __restrict__ outF,
                                                int ldOut) {
    __shared__ ushort As[128 * LDT];
    __shared__ ushort Bs[128 * LDT];
    int tid = threadIdx.x;
    int lane = tid & 63, wid = tid >> 6;
    int wm = wid & 1, wn = wid >> 1;
    int l15 = lane & 15, quad = lane >> 4;
    int bm = blockIdx.x, bn = blockIdx.y;
    const int K = DMODEL;

    f32x4 acc[4][4];
    #pragma unroll
    for (int i = 0; i < 4; i++)
        #pragma unroll
        for (int j = 0; j < 4; j++)
            acc[i][j] = (f32x4){0.f, 0.f, 0.f, 0.f};

    for (int kt = 0; kt < K; kt += 32) {
        __syncthreads();
        #pragma unroll
        for (int i = 0; i < 2; i++) {
            int ch = tid * 2 + i;
            int row = ch >> 2, q = ch & 3;
            uint4 av = ((const uint4*)A)[((bm * 128 + row) * K + kt) / 8 + q];
            *(uint4*)&As[row * LDT + q * 8] = av;
            uint4 bv = ((const uint4*)Bt)[((bn * 128 + row) * K + kt) / 8 + q];
            *(uint4*)&Bs[row * LDT + q * 8] = bv;
        }
        __syncthreads();
        short8 af[4], bf[4];
        #pragma unroll
        for (int i = 0; i < 4; i++) {
            af[i] = *(const short8*)&As[(wm * 64 + i * 16 + l15) * LDT + quad * 8];
            bf[i] = *(const short8*)&Bs[(wn * 64 + i * 16 + l15) * LDT + quad * 8];
        }
        #pragma unroll
        for (int mt = 0; mt < 4; mt++)
            #pragma unroll
            for (int nt = 0; nt < 4; nt++)
                acc[mt][nt] = __builtin_amdgcn_mfma_f32_16x16x32_bf16(
                    af[mt], bf[nt], acc[mt][nt], 0, 0, 0);
    }

    #pragma unroll
    for (int mt = 0; mt < 4; mt++)
        #pragma unroll
        for (int nt = 0; nt < 4; nt++)
            #pragma unroll
            for (int r = 0; r < 4; r++) {
                int row = bm * 128 + wm * 64 + mt * 16 + quad * 4 + r;
                int col = bn * 128 + wn * 64 + nt * 16 + l15;
                outF[(size_t)row * ldOut + col] = acc[mt][nt][r];
            }
}

// ---------------- causal depthwise conv(k=4) + silu (+ l2norm for q/k, q/=8) ----------------
__global__ void gdn_conv(const float* __restrict__ pre,
                         const float* __restrict__ cqw, const float* __restrict__ cqb,
                         const float* __restrict__ ckw, const float* __restrict__ ckb,
                         const float* __restrict__ cvw, const float* __restrict__ cvb,
                         float* __restrict__ qn, float* __restrict__ kn, float* __restrict__ vn) {
    int m = blockIdx.x;
    int which = blockIdx.y;        // 0:q 1:k 2:v
    int t = m & (TSEQ - 1);
    const float* cw = (which == 0) ? cqw : (which == 1) ? ckw : cvw;
    const float* cb = (which == 0) ? cqb : (which == 1) ? ckb : cvb;
    float* dst = (which == 0) ? qn : (which == 1) ? kn : vn;
    int c = threadIdx.x * 4;       // 4 consecutive channels

    float w[4][4];
    #pragma unroll
    for (int i = 0; i < 4; i++) {
        float4 t4 = ((const float4*)cw)[c + i];   // taps of channel c+i
        w[i][0] = t4.x; w[i][1] = t4.y; w[i][2] = t4.z; w[i][3] = t4.w;
    }
    float4 bias = ((const float4*)cb)[threadIdx.x];
    float y[4] = {bias.x, bias.y, bias.z, bias.w};

    const float* src = pre + (size_t)m * 4096 + which * 1024 + c;
    #pragma unroll
    for (int j = 0; j < 4; j++) {
        int tt = t - 3 + j;
        if (tt >= 0) {
            float4 xv = *(const float4*)(src + (long)(j - 3) * 4096);
            y[0] += xv.x * w[0][j];
            y[1] += xv.y * w[1][j];
            y[2] += xv.z * w[2][j];
            y[3] += xv.w * w[3][j];
        }
    }
    #pragma unroll
    for (int i = 0; i < 4; i++) y[i] = silu_f(y[i]);

    if (which < 2) {   // l2norm over 64-channel head groups (16 consecutive lanes)
        float ss = y[0]*y[0] + y[1]*y[1] + y[2]*y[2] + y[3]*y[3];
        ss += __shfl_xor(ss, 1);
        ss += __shfl_xor(ss, 2);
        ss += __shfl_xor(ss, 4);
        ss += __shfl_xor(ss, 8);
        float sc = rsqrtf(ss + 1e-6f);
        if (which == 0) sc *= 0.125f;   // q /= sqrt(d)
        #pragma unroll
        for (int i = 0; i < 4; i++) y[i] *= sc;
    }
    float4 o; o.x = y[0]; o.y = y[1]; o.z = y[2]; o.w = y[3];
    ((float4*)(dst + (size_t)m * 1024))[threadIdx.x] = o;
}

// ---------------- delta-rule recurrence ----------------
// grid: 512 blocks = (b, h, col-group cg in 0..15); 64 threads (1 wave).
// lane = col*16 + rq: col = lane>>4 in 0..3 (global column cg*4+col),
// rq = lane&15 owns rows rq*4..rq*4+3 (S = 4 floats). Row-of-16 DPP reduction.
// Double-buffered LDS chunks of RC=32 steps staged via global_load_lds.
// Output: otmp2[((b*NH+h)*16+cg)*TSEQ*4 + t*4 + col] (chunk-coalesced flush).
#define RC 32
__global__ __launch_bounds__(64) void gdn_recur(const float* __restrict__ qn,
                                                const float* __restrict__ kn,
                                                const float* __restrict__ vn,
                                                const float* __restrict__ betaT,
                                                float* __restrict__ otmp2) {
    __shared__ float k_lds[2][RC][64];
    __shared__ float q_lds[2][RC][64];
    __shared__ float v_lds[2][RC][4];
    __shared__ float o_lds[RC * 4];
    __shared__ float beta_lds[TSEQ];

    int blk = blockIdx.x;
    int cg = blk & 15;
    int h = (blk >> 4) & 15;
    int b = blk >> 8;
    int lane = threadIdx.x;
    int col = lane >> 4;
    int rq4 = (lane & 15) * 4;

    float S[4] = {0.f, 0.f, 0.f, 0.f};

    size_t base0 = (size_t)b * TSEQ * 1024 + h * 64;

    // per-lane global staging pointers (advance by RC*1024 per chunk)
    const float* kg = kn + base0 + (size_t)(lane >> 4) * 1024 + (lane & 15) * 4;
    const float* qg = qn + base0 + (size_t)(lane >> 4) * 1024 + (lane & 15) * 4;
    const float* vg = vn + base0 + (size_t)(lane >> 2) * 1024 + cg * 4 + (lane & 3);

    // preload all betas for this (b,h)
    {
        const float* bsrc = betaT + ((size_t)(b * NH + h) << 11);
        #pragma unroll
        for (int i = 0; i < TSEQ / 64; ++i)
            beta_lds[i * 64 + lane] = bsrc[i * 64 + lane];
    }

    #define ISSUE_CHUNK(T0, BUF)                                             \
        {                                                                    \
            _Pragma("unroll")                                                \
            for (int i = 0; i < RC / 4; i++) {                               \
                gl_lds16(kg + (size_t)((T0) + i * 4) * 1024,                 \
                         &k_lds[BUF][i * 4][0]);                             \
                gl_lds16(qg + (size_t)((T0) + i * 4) * 1024,                 \
                         &q_lds[BUF][i * 4][0]);                             \
            }                                                                \
            _Pragma("unroll")                                                \
            for (int j = 0; j < RC / 16; j++)                                \
                gl_lds4(vg + (size_t)((T0) + j * 16) * 1024,                 \
                        &v_lds[BUF][j * 16][0]);                             \
        }

    ISSUE_CHUNK(0, 0);
    __syncthreads();   // waits vmcnt(0): chunk 0 resident

    float* ob = otmp2 + (size_t)((b * NH + h) * 16 + cg) * (TSEQ * 4);

    for (int c = 0; c < TSEQ / RC; ++c) {
        if (c + 1 < TSEQ / RC) ISSUE_CHUNK((c + 1) * RC, (c + 1) & 1);

        const float* kb = &k_lds[c & 1][0][0];
        const float* qb = &q_lds[c & 1][0][0];
        const float* vb = &v_lds[c & 1][0][0];
        const float* bb = &beta_lds[c * RC];

        #pragma unroll
        for (int t = 0; t < RC; ++t) {
            float4 kf = *(const float4*)&kb[t * 64 + rq4];
            float4 qf = *(const float4*)&qb[t * 64 + rq4];
            float vv = vb[t * 4 + col];
            float bt = bb[t];

            float p0 = kf.x * S[0];
            float p1 = kf.y * S[1];
            float p2 = kf.z * S[2];
            float p3 = kf.w * S[3];
            float pk = red16((p0 + p1) + (p2 + p3));
            float err = (vv - pk) * bt;

            S[0] += kf.x * err;
            S[1] += kf.y * err;
            S[2] += kf.z * err;
            S[3] += kf.w * err;
            float q0 = qf.x * S[0];
            float q1 = qf.y * S[1];
            float q2 = qf.z * S[2];
            float q3 = qf.w * S[3];
            float pq = red16((q0 + q1) + (q2 + q3));
            if ((lane & 15) == 0) o_lds[t * 4 + col] = pq;
        }
        __syncthreads();   // drains next-chunk loads (already landed) + LDS order
        // coalesced flush: 128 contiguous floats
        ob[c * (RC * 4) + lane] = o_lds[lane];
        ob[c * (RC * 4) + 64 + lane] = o_lds[64 + lane];
    }
    #undef ISSUE_CHUNK
}

// ---------------- RMSNorm * nw * silu(gate) -> bf16 ----------------
__global__ void gdn_fuse(const float* __restrict__ otmp2, const float* __restrict__ pre,
                         const float* __restrict__ nw, ushort* __restrict__ ofused) {
    int m = blockIdx.x;
    int b = m >> 11, t = m & (TSEQ - 1);
    int tid = threadIdx.x;
    // thread tid covers channels tid*4..tid*4+3 = head (tid>>4), col-group (tid&15)
    float4 o = ((const float4*)otmp2)[((size_t)((b * NH + (tid >> 4)) * 16 + (tid & 15))) * TSEQ + t];
    float ss = o.x*o.x + o.y*o.y + o.z*o.z + o.w*o.w;
    ss += __shfl_xor(ss, 1);
    ss += __shfl_xor(ss, 2);
    ss += __shfl_xor(ss, 4);
    ss += __shfl_xor(ss, 8);
    float r = rsqrtf(ss * (1.f / 64.f) + 1e-5f);
    float4 nwv = ((const float4*)nw)[tid & 15];
    float4 g = ((const float4*)(pre + (size_t)m * 4096 + 3072))[tid];
    ushort4 out;
    out.x = f2bf(o.x * r * nwv.x * silu_f(g.x));
    out.y = f2bf(o.y * r * nwv.y * silu_f(g.y));
    out.z = f2bf(o.z * r * nwv.z * silu_f(g.z));
    out.w = f2bf(o.w * r * nwv.w * silu_f(g.w));
    ((ushort4*)ofused)[m * 256 + tid] = out;
}

extern "C" void kernel_launch(void* const* d_in, const int* in_sizes, int n_in,
                              void* d_out, int out_size, void* d_ws, size_t ws_size,
                              hipStream_t stream) {
    const float* x    = (const float*)d_in[0];
    const float* Wq   = (const float*)d_in[1];
    const float* Wk   = (const float*)d_in[2];
    const float* Wv   = (const float*)d_in[3];
    const float* Wo   = (const float*)d_in[4];
    const float* Wg   = (const float*)d_in[5];
    const float* Wb   = (const float*)d_in[6];
    const float* cq_w = (const float*)d_in[7];
    const float* cq_b = (const float*)d_in[8];
    const float* ck_w = (const float*)d_in[9];
    const float* ck_b = (const float*)d_in[10];
    const float* cv_w = (const float*)d_in[11];
    const float* cv_b = (const float*)d_in[12];
    const float* nw   = (const float*)d_in[13];

    char* ws = (char*)d_ws;
    ushort* xb     = (ushort*)(ws);                       // 8 MB
    ushort* wt     = (ushort*)(ws + 8388608);             // 10 MB (5 transposed bf16 weights)
    float*  pre    = (float*)(ws + 18874368);             // 64 MB  [4096][4096] q|k|v|g
    float*  qn     = (float*)(ws + 85983232);             // 16 MB
    float*  kn     = (float*)(ws + 102760448);            // 16 MB
    float*  vn     = (float*)(ws + 119537664);            // 16 MB
    float*  betaT  = (float*)(ws + 136314880);            // 256 KB
    float*  otmp2  = (float*)(ws + 136577024);            // 16 MB
    ushort* ofused = (ushort*)(ws + 153354240);           // 8 MB  (total ~161.4 MB)

    // 1. x -> bf16
    gdn_cvt_x<<<4096, 256, 0, stream>>>(x, xb);
    // 2. transpose+convert 5 weights
    gdn_cvt_w<<<dim3(32, 32, 5), dim3(32, 8), 0, stream>>>(Wq, Wk, Wv, Wg, Wo, wt);
    // 3. betaT (fp32 exact, transposed layout)
    gdn_beta<<<256, 256, 0, stream>>>(x, Wb, betaT);
    // 4. fused q/k/v/g pre-activation GEMM: [4096][4096] fp32
    gdn_gemm<<<dim3(32, 32), 256, 0, stream>>>(xb, wt, pre, 4096);
    // 5. conv + silu (+ l2norm)
    gdn_conv<<<dim3(4096, 3), 256, 0, stream>>>(pre, cq_w, cq_b, ck_w, ck_b, cv_w, cv_b,
                                                qn, kn, vn);
    // 6. delta-rule recurrence (512 blocks, 4 rows/lane, async LDS double-buffer)
    gdn_recur<<<512, 64, 0, stream>>>(qn, kn, vn, betaT, otmp2);
    // 7. RMSNorm * nw * silu(gate) -> bf16
    gdn_fuse<<<4096, 256, 0, stream>>>(otmp2, pre, nw, ofused);
    // 8. final GEMM -> d_out (fp32 output)
    gdn_gemm<<<dim3(32, 8), 256, 0, stream>>>(ofused, wt + 4 * 1024 * 1024,
                                              (float*)d_out, 1024);
}

// Round 8
// 519.515 us; speedup vs baseline: 2.9545x; 1.0535x over previous
//
#include <hip/hip_runtime.h>
#include <hip/hip_bf16.h>

typedef __attribute__((ext_vector_type(8))) short short8;
typedef __attribute__((ext_vector_type(4))) float f32x4;

#define TSEQ 2048
#define DMODEL 1024
#define NH 16
#define HD 64

__device__ __forceinline__ ushort f2bf(float f) {
    union { float f; unsigned int u; } c; c.f = f;
    unsigned int u = c.u + 0x7fffu + ((c.u >> 16) & 1u);   // RNE
    return (ushort)(u >> 16);
}

__device__ __forceinline__ float silu_f(float y) {
    return y / (1.f + __expf(-y));
}

// DPP helpers. ctrl must be a constant expression -> template parameter.
template <int CTRL>
__device__ __forceinline__ float dpp_add(float x) {
    return x + __int_as_float(__builtin_amdgcn_update_dpp(
        0, __float_as_int(x), CTRL, 0xF, 0xF, true));
}
// Reduction over a row of 16 lanes.
__device__ __forceinline__ float red16(float x) {
    x = dpp_add<0xB1>(x);    // quad_perm xor 1
    x = dpp_add<0x4E>(x);    // quad_perm xor 2
    x = dpp_add<0x141>(x);   // row_half_mirror
    x = dpp_add<0x140>(x);   // row_mirror
    return x;
}

// async global->LDS (dest = uniform base + lane*size)
__device__ __forceinline__ void gl_lds16(const float* g, float* l) {
    __builtin_amdgcn_global_load_lds(
        (__attribute__((address_space(1))) void*)g,
        (__attribute__((address_space(3))) void*)l, 16, 0, 0);
}
__device__ __forceinline__ void gl_lds4(const float* g, float* l) {
    __builtin_amdgcn_global_load_lds(
        (__attribute__((address_space(1))) void*)g,
        (__attribute__((address_space(3))) void*)l, 4, 0, 0);
}

// ---------------- convert x -> bf16 ----------------
__global__ void gdn_cvt_x(const float* __restrict__ x, ushort* __restrict__ xb) {
    int i = blockIdx.x * 256 + threadIdx.x;           // one float4 per thread
    float4 v = ((const float4*)x)[i];
    ushort4 o;
    o.x = f2bf(v.x); o.y = f2bf(v.y); o.z = f2bf(v.z); o.w = f2bf(v.w);
    ((ushort4*)xb)[i] = o;
}

// ------------- transpose+convert weights: W[k][n] f32 -> wt[z][n][k] bf16 -------------
__global__ void gdn_cvt_w(const float* __restrict__ Wq, const float* __restrict__ Wk,
                          const float* __restrict__ Wv, const float* __restrict__ Wg,
                          const float* __restrict__ Wo, ushort* __restrict__ wt) {
    __shared__ float tile[32][33];
    int z = blockIdx.z;
    const float* W = (z == 0) ? Wq : (z == 1) ? Wk : (z == 2) ? Wv : (z == 3) ? Wg : Wo;
    int n0 = blockIdx.x * 32, k0 = blockIdx.y * 32;
    int tx = threadIdx.x, ty = threadIdx.y;           // (32, 8)
    #pragma unroll
    for (int j = 0; j < 32; j += 8)
        tile[ty + j][tx] = W[(size_t)(k0 + ty + j) * DMODEL + n0 + tx];
    __syncthreads();
    ushort* o = wt + (size_t)z * DMODEL * DMODEL;
    #pragma unroll
    for (int j = 0; j < 32; j += 8)
        o[(size_t)(n0 + ty + j) * DMODEL + k0 + tx] = f2bf(tile[tx][ty + j]);
}

// ---------------- betaT[(b*NH+h)*TSEQ + t] = sigmoid(x @ Wb), fp32 exact ----------------
// Block: 256 threads = 16 m-rows x 16 heads; x rows staged in LDS (coalesced).
__global__ void gdn_beta(const float* __restrict__ x, const float* __restrict__ Wb,
                         float* __restrict__ betaT) {
    __shared__ float xs[16][DMODEL];
    int tid = threadIdx.x;
    int m0 = blockIdx.x * 16;
    // stage 16 rows: 4096 float4s, 16 per thread
    #pragma unroll
    for (int i = 0; i < 16; i++) {
        int idx = i * 256 + tid;                 // float4 index
        int row = idx >> 8, c4 = idx & 255;
        *(float4*)&xs[row][c4 * 4] =
            *(const float4*)&x[(size_t)(m0 + row) * DMODEL + c4 * 4];
    }
    __syncthreads();
    int h = tid & 15, mi = tid >> 4;
    float acc = 0.f;
    for (int k = 0; k < DMODEL; ++k)             // same order as before (numerics)
        acc += xs[mi][k] * Wb[k * NH + h];
    int m = m0 + mi;
    int b = m >> 11, t = m & (TSEQ - 1);
    betaT[((b * NH + h) << 11) + t] = 1.f / (1.f + __expf(-acc));
}

// ---------------- bf16 MFMA GEMM: out[M][ldOut] = A[M][1024] * Bt[N][1024]^T ----------------
#define LDT 40
__global__ __launch_bounds__(256) void gdn_gemm(const ushort* __restrict__ A,
                                                const ushort* __restrict__ Bt,
                                                float* __restrict__ outF,
                                                int ldOut) {
    __shared__ ushort As[128 * LDT];
    __shared__ ushort Bs[128 * LDT];
    int tid = threadIdx.x;
    int lane = tid & 63, wid = tid >> 6;
    int wm = wid & 1, wn = wid >> 1;
    int l15 = lane & 15, quad = lane >> 4;
    int bm = blockIdx.x, bn = blockIdx.y;
    const int K = DMODEL;

    f32x4 acc[4][4];
    #pragma unroll
    for (int i = 0; i < 4; i++)
        #pragma unroll
        for (int j = 0; j < 4; j++)
            acc[i][j] = (f32x4){0.f, 0.f, 0.f, 0.f};

    for (int kt = 0; kt < K; kt += 32) {
        __syncthreads();
        #pragma unroll
        for (int i = 0; i < 2; i++) {
            int ch = tid * 2 + i;
            int row = ch >> 2, q = ch & 3;
            uint4 av = ((const uint4*)A)[((bm * 128 + row) * K + kt) / 8 + q];
            *(uint4*)&As[row * LDT + q * 8] = av;
            uint4 bv = ((const uint4*)Bt)[((bn * 128 + row) * K + kt) / 8 + q];
            *(uint4*)&Bs[row * LDT + q * 8] = bv;
        }
        __syncthreads();
        short8 af[4], bf[4];
        #pragma unroll
        for (int i = 0; i < 4; i++) {
            af[i] = *(const short8*)&As[(wm * 64 + i * 16 + l15) * LDT + quad * 8];
            bf[i] = *(const short8*)&Bs[(wn * 64 + i * 16 + l15) * LDT + quad * 8];
        }
        #pragma unroll
        for (int mt = 0; mt < 4; mt++)
            #pragma unroll
            for (int nt = 0; nt < 4; nt++)
                acc[mt][nt] = __builtin_amdgcn_mfma_f32_16x16x32_bf16(
                    af[mt], bf[nt], acc[mt][nt], 0, 0, 0);
    }

    #pragma unroll
    for (int mt = 0; mt < 4; mt++)
        #pragma unroll
        for (int nt = 0; nt < 4; nt++)
            #pragma unroll
            for (int r = 0; r < 4; r++) {
                int row = bm * 128 + wm * 64 + mt * 16 + quad * 4 + r;
                int col = bn * 128 + wn * 64 + nt * 16 + l15;
                outF[(size_t)row * ldOut + col] = acc[mt][nt][r];
            }
}

// ---------------- causal depthwise conv(k=4) + silu (+ l2norm for q/k, q/=8) ----------------
__global__ void gdn_conv(const float* __restrict__ pre,
                         const float* __restrict__ cqw, const float* __restrict__ cqb,
                         const float* __restrict__ ckw, const float* __restrict__ ckb,
                         const float* __restrict__ cvw, const float* __restrict__ cvb,
                         float* __restrict__ qn, float* __restrict__ kn, float* __restrict__ vn) {
    int m = blockIdx.x;
    int which = blockIdx.y;        // 0:q 1:k 2:v
    int t = m & (TSEQ - 1);
    const float* cw = (which == 0) ? cqw : (which == 1) ? ckw : cvw;
    const float* cb = (which == 0) ? cqb : (which == 1) ? ckb : cvb;
    float* dst = (which == 0) ? qn : (which == 1) ? kn : vn;
    int c = threadIdx.x * 4;       // 4 consecutive channels

    float w[4][4];
    #pragma unroll
    for (int i = 0; i < 4; i++) {
        float4 t4 = ((const float4*)cw)[c + i];   // taps of channel c+i
        w[i][0] = t4.x; w[i][1] = t4.y; w[i][2] = t4.z; w[i][3] = t4.w;
    }
    float4 bias = ((const float4*)cb)[threadIdx.x];
    float y[4] = {bias.x, bias.y, bias.z, bias.w};

    const float* src = pre + (size_t)m * 4096 + which * 1024 + c;
    #pragma unroll
    for (int j = 0; j < 4; j++) {
        int tt = t - 3 + j;
        if (tt >= 0) {
            float4 xv = *(const float4*)(src + (long)(j - 3) * 4096);
            y[0] += xv.x * w[0][j];
            y[1] += xv.y * w[1][j];
            y[2] += xv.z * w[2][j];
            y[3] += xv.w * w[3][j];
        }
    }
    #pragma unroll
    for (int i = 0; i < 4; i++) y[i] = silu_f(y[i]);

    if (which < 2) {   // l2norm over 64-channel head groups (16 consecutive lanes)
        float ss = y[0]*y[0] + y[1]*y[1] + y[2]*y[2] + y[3]*y[3];
        ss += __shfl_xor(ss, 1);
        ss += __shfl_xor(ss, 2);
        ss += __shfl_xor(ss, 4);
        ss += __shfl_xor(ss, 8);
        float sc = rsqrtf(ss + 1e-6f);
        if (which == 0) sc *= 0.125f;   // q /= sqrt(d)
        #pragma unroll
        for (int i = 0; i < 4; i++) y[i] *= sc;
    }
    float4 o; o.x = y[0]; o.y = y[1]; o.z = y[2]; o.w = y[3];
    ((float4*)(dst + (size_t)m * 1024))[threadIdx.x] = o;
}

// ---------------- delta-rule recurrence ----------------
// grid: 512 blocks = (b, h, col-group cg in 0..15); 64 threads (1 wave).
// lane = col*16 + rq. Register-level software pipeline: ds_reads for step t+1
// issue during step t's compute chain (parity-indexed register double-buffer).
#define RC 32
__global__ __launch_bounds__(64) void gdn_recur(const float* __restrict__ qn,
                                                const float* __restrict__ kn,
                                                const float* __restrict__ vn,
                                                const float* __restrict__ betaT,
                                                float* __restrict__ otmp2) {
    __shared__ float k_lds[2][RC][64];
    __shared__ float q_lds[2][RC][64];
    __shared__ float v_lds[2][RC][4];
    __shared__ float o_lds[RC * 4];
    __shared__ float beta_lds[TSEQ];

    int blk = blockIdx.x;
    int cg = blk & 15;
    int h = (blk >> 4) & 15;
    int b = blk >> 8;
    int lane = threadIdx.x;
    int col = lane >> 4;
    int rq4 = (lane & 15) * 4;

    float S[4] = {0.f, 0.f, 0.f, 0.f};

    size_t base0 = (size_t)b * TSEQ * 1024 + h * 64;

    const float* kg = kn + base0 + (size_t)(lane >> 4) * 1024 + (lane & 15) * 4;
    const float* qg = qn + base0 + (size_t)(lane >> 4) * 1024 + (lane & 15) * 4;
    const float* vg = vn + base0 + (size_t)(lane >> 2) * 1024 + cg * 4 + (lane & 3);

    // preload all betas for this (b,h)
    {
        const float* bsrc = betaT + ((size_t)(b * NH + h) << 11);
        #pragma unroll
        for (int i = 0; i < TSEQ / 64; ++i)
            beta_lds[i * 64 + lane] = bsrc[i * 64 + lane];
    }

    #define ISSUE_CHUNK(T0, BUF)                                             \
        {                                                                    \
            _Pragma("unroll")                                                \
            for (int i = 0; i < RC / 4; i++) {                               \
                gl_lds16(kg + (size_t)((T0) + i * 4) * 1024,                 \
                         &k_lds[BUF][i * 4][0]);                             \
                gl_lds16(qg + (size_t)((T0) + i * 4) * 1024,                 \
                         &q_lds[BUF][i * 4][0]);                             \
            }                                                                \
            _Pragma("unroll")                                                \
            for (int j = 0; j < RC / 16; j++)                                \
                gl_lds4(vg + (size_t)((T0) + j * 16) * 1024,                 \
                        &v_lds[BUF][j * 16][0]);                             \
        }

    ISSUE_CHUNK(0, 0);
    __syncthreads();   // waits vmcnt(0): chunk 0 resident

    float* ob = otmp2 + (size_t)((b * NH + h) * 16 + cg) * (TSEQ * 4);

    for (int c = 0; c < TSEQ / RC; ++c) {
        if (c + 1 < TSEQ / RC) ISSUE_CHUNK((c + 1) * RC, (c + 1) & 1);

        const float* kb = &k_lds[c & 1][0][0];
        const float* qb = &q_lds[c & 1][0][0];
        const float* vb = &v_lds[c & 1][0][0];
        const float* bb = &beta_lds[c * RC];

        // register pipeline: preload step 0
        float4 kreg[2], qreg[2];
        float vreg[2], breg[2];
        kreg[0] = *(const float4*)&kb[rq4];
        qreg[0] = *(const float4*)&qb[rq4];
        vreg[0] = vb[col];
        breg[0] = bb[0];

        #pragma unroll
        for (int t = 0; t < RC; ++t) {
            int cur = t & 1, nxt = cur ^ 1;
            if (t + 1 < RC) {      // issue next step's LDS reads before the chain
                kreg[nxt] = *(const float4*)&kb[(t + 1) * 64 + rq4];
                qreg[nxt] = *(const float4*)&qb[(t + 1) * 64 + rq4];
                vreg[nxt] = vb[(t + 1) * 4 + col];
                breg[nxt] = bb[t + 1];
            }
            float4 kf = kreg[cur];
            float4 qf = qreg[cur];
            float vv = vreg[cur];
            float bt = breg[cur];

            float p0 = kf.x * S[0];
            float p1 = kf.y * S[1];
            float p2 = kf.z * S[2];
            float p3 = kf.w * S[3];
            float pk = red16((p0 + p1) + (p2 + p3));
            float err = (vv - pk) * bt;

            S[0] += kf.x * err;
            S[1] += kf.y * err;
            S[2] += kf.z * err;
            S[3] += kf.w * err;
            float q0 = qf.x * S[0];
            float q1 = qf.y * S[1];
            float q2 = qf.z * S[2];
            float q3 = qf.w * S[3];
            float pq = red16((q0 + q1) + (q2 + q3));
            if ((lane & 15) == 0) o_lds[t * 4 + col] = pq;
        }
        __syncthreads();   // chunk c+1 resident; o_lds complete
        // coalesced flush: 128 contiguous floats
        ob[c * (RC * 4) + lane] = o_lds[lane];
        ob[c * (RC * 4) + 64 + lane] = o_lds[64 + lane];
    }
    #undef ISSUE_CHUNK
}

// ---------------- RMSNorm * nw * silu(gate) -> bf16 ----------------
__global__ void gdn_fuse(const float* __restrict__ otmp2, const float* __restrict__ pre,
                         const float* __restrict__ nw, ushort* __restrict__ ofused) {
    int m = blockIdx.x;
    int b = m >> 11, t = m & (TSEQ - 1);
    int tid = threadIdx.x;
    float4 o = ((const float4*)otmp2)[((size_t)((b * NH + (tid >> 4)) * 16 + (tid & 15))) * TSEQ + t];
    float ss = o.x*o.x + o.y*o.y + o.z*o.z + o.w*o.w;
    ss += __shfl_xor(ss, 1);
    ss += __shfl_xor(ss, 2);
    ss += __shfl_xor(ss, 4);
    ss += __shfl_xor(ss, 8);
    float r = rsqrtf(ss * (1.f / 64.f) + 1e-5f);
    float4 nwv = ((const float4*)nw)[tid & 15];
    float4 g = ((const float4*)(pre + (size_t)m * 4096 + 3072))[tid];
    ushort4 out;
    out.x = f2bf(o.x * r * nwv.x * silu_f(g.x));
    out.y = f2bf(o.y * r * nwv.y * silu_f(g.y));
    out.z = f2bf(o.z * r * nwv.z * silu_f(g.z));
    out.w = f2bf(o.w * r * nwv.w * silu_f(g.w));
    ((ushort4*)ofused)[m * 256 + tid] = out;
}

extern "C" void kernel_launch(void* const* d_in, const int* in_sizes, int n_in,
                              void* d_out, int out_size, void* d_ws, size_t ws_size,
                              hipStream_t stream) {
    const float* x    = (const float*)d_in[0];
    const float* Wq   = (const float*)d_in[1];
    const float* Wk   = (const float*)d_in[2];
    const float* Wv   = (const float*)d_in[3];
    const float* Wo   = (const float*)d_in[4];
    const float* Wg   = (const float*)d_in[5];
    const float* Wb   = (const float*)d_in[6];
    const float* cq_w = (const float*)d_in[7];
    const float* cq_b = (const float*)d_in[8];
    const float* ck_w = (const float*)d_in[9];
    const float* ck_b = (const float*)d_in[10];
    const float* cv_w = (const float*)d_in[11];
    const float* cv_b = (const float*)d_in[12];
    const float* nw   = (const float*)d_in[13];

    char* ws = (char*)d_ws;
    ushort* xb     = (ushort*)(ws);                       // 8 MB
    ushort* wt     = (ushort*)(ws + 8388608);             // 10 MB (5 transposed bf16 weights)
    float*  pre    = (float*)(ws + 18874368);             // 64 MB  [4096][4096] q|k|v|g
    float*  qn     = (float*)(ws + 85983232);             // 16 MB
    float*  kn     = (float*)(ws + 102760448);            // 16 MB
    float*  vn     = (float*)(ws + 119537664);            // 16 MB
    float*  betaT  = (float*)(ws + 136314880);            // 256 KB
    float*  otmp2  = (float*)(ws + 136577024);            // 16 MB
    ushort* ofused = (ushort*)(ws + 153354240);           // 8 MB  (total ~161.4 MB)

    // 1. x -> bf16
    gdn_cvt_x<<<4096, 256, 0, stream>>>(x, xb);
    // 2. transpose+convert 5 weights
    gdn_cvt_w<<<dim3(32, 32, 5), dim3(32, 8), 0, stream>>>(Wq, Wk, Wv, Wg, Wo, wt);
    // 3. betaT (fp32 exact, LDS-staged x)
    gdn_beta<<<256, 256, 0, stream>>>(x, Wb, betaT);
    // 4. fused q/k/v/g pre-activation GEMM: [4096][4096] fp32
    gdn_gemm<<<dim3(32, 32), 256, 0, stream>>>(xb, wt, pre, 4096);
    // 5. conv + silu (+ l2norm)
    gdn_conv<<<dim3(4096, 3), 256, 0, stream>>>(pre, cq_w, cq_b, ck_w, ck_b, cv_w, cv_b,
                                                qn, kn, vn);
    // 6. delta-rule recurrence (register-pipelined LDS reads)
    gdn_recur<<<512, 64, 0, stream>>>(qn, kn, vn, betaT, otmp2);
    // 7. RMSNorm * nw * silu(gate) -> bf16
    gdn_fuse<<<4096, 256, 0, stream>>>(otmp2, pre, nw, ofused);
    // 8. final GEMM -> d_out (fp32 output)
    gdn_gemm<<<dim3(32, 8), 256, 0, stream>>>(ofused, wt + 4 * 1024 * 1024,
                                              (float*)d_out, 1024);
}